// Round 14
// baseline (126.538 us; speedup 1.0000x reference)
//
#include <hip/hip_runtime.h>
#include <hip/hip_bf16.h>

#define T_TOK 2048
#define H_DIM 1024
#define I_DIM 768
#define NEXP  8
#define XSTR  1056   // padded row stride in shorts (2112B)
#define WSTR  1056

typedef short bf16x8  __attribute__((ext_vector_type(8)));
typedef short short4v __attribute__((ext_vector_type(4)));
typedef float f32x4   __attribute__((ext_vector_type(4)));

__device__ __forceinline__ short f2bf(float f) {
  __bf16 b = (__bf16)f;
  return __builtin_bit_cast(short, b);
}
__device__ __forceinline__ void gload16(const void* g, void* l) {
  __builtin_amdgcn_global_load_lds(
      (const __attribute__((address_space(1))) void*)g,
      (__attribute__((address_space(3))) void*)l, 16, 0, 0);
}
__device__ __forceinline__ void ntst(unsigned short* p, short4v v) {
  __builtin_nontemporal_store(v, (short4v*)p);
}
__device__ __forceinline__ void ntstf(float* p, f32x4 v) {
  __builtin_nontemporal_store(v, (f32x4*)p);
}
__device__ __forceinline__ int padcnt(int c) { return (c + 63) & ~63; }
__device__ __forceinline__ int ebase(const int* __restrict__ cnts, int e) {
  int b = 0;
#pragma unroll
  for (int i = 0; i < NEXP; ++i)
    if (i < e) b += padcnt(cnts[i]);
  return b;
}

// ws layout (bytes):
// 0: counts[8] | 256: lists[8*2048] | 131072: x_bf [2049][1056] (row 2048 = zeros)
// 4458560: gate_bf [6144][1056] | 17434688: up_bf [6144][1056]
// 30410816: down_bf [8192][768] | 42993728: h [5120][768]

// ---- kernel A: routing compaction; pad entries -> token 2048 (zero row)
__global__ __launch_bounds__(512) void compact_k(const float* __restrict__ routw,
                                                 int* __restrict__ wsI) {
  __shared__ int sc[8];
  int e = blockIdx.x, tid = threadIdx.x, lane = tid & 63, w = tid >> 6;
  unsigned long long mk[4];
  int cnt = 0;
#pragma unroll
  for (int c = 0; c < 4; ++c) {
    int tk = w * 256 + c * 64 + lane;
    float v = routw[(size_t)tk * NEXP + e];
    mk[c] = __ballot(v > 0.f);
    cnt += __popcll(mk[c]);
  }
  if (lane == 0) sc[w] = cnt;
  __syncthreads();
  int run = 0, tot = 0;
#pragma unroll
  for (int j = 0; j < 8; ++j) {
    if (j < w) run += sc[j];
    tot += sc[j];
  }
#pragma unroll
  for (int c = 0; c < 4; ++c) {
    int tk = w * 256 + c * 64 + lane;
    if ((mk[c] >> lane) & 1ull) {
      int pos = __popcll(mk[c] & ((1ull << lane) - 1));
      wsI[64 + e * T_TOK + run + pos] = tk;
    }
    run += __popcll(mk[c]);
  }
  if (w == 7 && lane == 0) wsI[e] = tot;
  int pad = padcnt(tot);
  for (int r = tot + tid; r < pad; r += 512) wsI[64 + e * T_TOK + r] = T_TOK;  // zero row
}

// ---- kernel B: all conversions + zerofill; ALL stores non-temporal (LLC-clean,
// avoids dirty-line cross-XCD reads in the GEMMs).
// [0,520): x rows 0..2048 | [520,2056): gate | [2056,3592): up | [3592,5128): down
// [5128,5640): zerofill out
__global__ __launch_bounds__(256) void pre_k(const float* __restrict__ x,
                                             const float* __restrict__ gw,
                                             const float* __restrict__ uw,
                                             const float* __restrict__ dw,
                                             unsigned short* __restrict__ x_bf,
                                             unsigned short* __restrict__ gbf,
                                             unsigned short* __restrict__ ubf,
                                             unsigned short* __restrict__ dbf,
                                             float* __restrict__ out) {
  int bid = blockIdx.x, tid = threadIdx.x;
  int col = (tid & 63) * 16;
  if (bid < 520) {
    int r = bid * 4 + (tid >> 6);
    if (r > 2048) return;
    unsigned short* dst = x_bf + (size_t)r * XSTR + col;
    if (r < 2048) {
      const float* sr = x + (size_t)r * H_DIM + col;
#pragma unroll
      for (int j = 0; j < 4; ++j) {
        float4 v = *(const float4*)(sr + j * 4);
        short4v b = {f2bf(v.x), f2bf(v.y), f2bf(v.z), f2bf(v.w)};
        ntst(dst + j * 4, b);
      }
    } else {
      short4v z = {0, 0, 0, 0};
#pragma unroll
      for (int j = 0; j < 4; ++j) ntst(dst + j * 4, z);
    }
  } else if (bid < 3592) {
    int a = (bid < 2056) ? 0 : 1;
    int r = (bid - (a ? 2056 : 520)) * 4 + (tid >> 6);
    const float* s = (a ? uw : gw) + (size_t)r * H_DIM + col;
    unsigned short* dst = (a ? ubf : gbf) + (size_t)r * WSTR + col;
#pragma unroll
    for (int j = 0; j < 4; ++j) {
      float4 v = *(const float4*)(s + j * 4);
      short4v b = {f2bf(v.x), f2bf(v.y), f2bf(v.z), f2bf(v.w)};
      ntst(dst + j * 4, b);
    }
  } else if (bid < 5128) {
    size_t off = ((size_t)(bid - 3592) * 256 + tid) * 16;
    const float* s = dw + off;
    unsigned short* o = dbf + off;
#pragma unroll
    for (int j = 0; j < 4; ++j) {
      float4 v = *(const float4*)(s + j * 4);
      short4v b = {f2bf(v.x), f2bf(v.y), f2bf(v.z), f2bf(v.w)};
      ntst(o + j * 4, b);
    }
  } else {
    size_t off = ((size_t)(bid - 5128) * 256 + tid) * 16;
    f32x4 z = {0.f, 0.f, 0.f, 0.f};
#pragma unroll
    for (int j = 0; j < 4; ++j) ntstf(out + off + j * 4, z);
  }
}

// ---- kernel C: gemm1 in the m97 CO-RESIDENCY regime.
// h = silu(X Wg^T)*(X Wu^T). Tile M64 x (G64++U64), BK=32, 256 thr / 4 waves,
// wave tile 32x64 (8 MFMA : 6 ds_read). LDS dbuf 2x12KB = 24KB; VGPR<=128 via
// launch_bounds -> 4 blocks x 4 waves = 16 waves/CU co-resident (the m114 engine).
// Plain 2-phase loop (m97). grid = 8e * 32mt * 12ng = 3072, active ~768 (3/CU).
__global__ __launch_bounds__(256, 4) void gemm1_k(
    const unsigned short* __restrict__ x_bf, const unsigned short* __restrict__ gbf,
    const unsigned short* __restrict__ ubf, const int* __restrict__ wsI,
    unsigned short* __restrict__ h) {
  int e = blockIdx.x & 7, rr = blockIdx.x >> 3;
  int mt = rr & 31, ng = rr >> 5;       // mt 0..31, ng 0..11
  int cnt = wsI[e];
  int m0 = mt * 64;
  if (m0 >= cnt) return;
  int base = ebase(wsI, e);
  int g0 = ng * 64;

  __shared__ unsigned short ls[2][6144];  // A[64][32]@0, B[128][32]@2048 (G64++U64)

  int tid = threadIdx.x, lane = tid & 63, w = tid >> 6;   // 4 waves
  int wm = w >> 1, wn = w & 1;
  int fr = lane & 15, fg = lane >> 4;
  int srow = lane >> 2;
  int scol = ((lane & 3) ^ (srow & 3) ^ ((srow >> 2) & 1)) * 8;  // inverse swizzle on source

  // staging: 12 chunks of 1KB (16 rows x 64B); wave w -> chunks {w, w+4, w+8}
  // chunk 0-3: A (per-lane token gather), 4-7: G rows, 8-11: U rows
  const unsigned short* src[3];
  int ldo[3];
  {
    int tok = wsI[64 + e * T_TOK + m0 + 16 * w + srow];   // pad rows -> token 2048 (zeros)
    src[0] = x_bf + (size_t)tok * XSTR + scol;
    ldo[0] = w * 512;
    src[1] = gbf + (size_t)(e * I_DIM + g0 + 16 * w + srow) * WSTR + scol;
    ldo[1] = (w + 4) * 512;
    src[2] = ubf + (size_t)(e * I_DIM + g0 + 16 * w + srow) * WSTR + scol;
    ldo[2] = (w + 8) * 512;
  }

  int sl = ((fg ^ (fr & 3) ^ ((fr >> 2) & 1)) << 3);
  int roA[2], roB[4];
#pragma unroll
  for (int m = 0; m < 2; ++m) roA[m] = (wm * 32 + m * 16 + fr) * 32 + sl;
#pragma unroll
  for (int n = 0; n < 4; ++n) {
    int r2 = (n < 2) ? (wn * 32 + n * 16 + fr) : (64 + wn * 32 + (n - 2) * 16 + fr);
    roB[n] = 2048 + r2 * 32 + sl;
  }

  f32x4 acc[2][4] = {};   // [m][n]: n 0,1 = G; 2,3 = U

#define STG1(buf, k)                                                 \
  do {                                                               \
    _Pragma("unroll") for (int i = 0; i < 3; ++i)                    \
      gload16(src[i] + (k) * 32, &ls[buf][ldo[i]]);                  \
  } while (0)

  STG1(0, 0);
  __syncthreads();
  for (int k = 0; k < 32; ++k) {
    int cur = k & 1;
    if (k + 1 < 32) STG1(cur ^ 1, k + 1);
    bf16x8 af[2], bv[4];
#pragma unroll
    for (int m = 0; m < 2; ++m) af[m] = *(const bf16x8*)&ls[cur][roA[m]];
#pragma unroll
    for (int n = 0; n < 4; ++n) bv[n] = *(const bf16x8*)&ls[cur][roB[n]];
#pragma unroll
    for (int m = 0; m < 2; ++m)
#pragma unroll
      for (int n = 0; n < 4; ++n)
        acc[m][n] = __builtin_amdgcn_mfma_f32_16x16x32_bf16(af[m], bv[n], acc[m][n], 0, 0, 0);
    __syncthreads();
  }
#undef STG1

#pragma unroll
  for (int m = 0; m < 2; ++m)
#pragma unroll
    for (int j = 0; j < 4; ++j) {
      int row = wm * 32 + m * 16 + fg * 4 + j;   // C/D: col=lane&15, row=(lane>>4)*4+reg
      size_t rb2 = (size_t)(base + m0 + row) * I_DIM + g0;
#pragma unroll
      for (int jn = 0; jn < 2; ++jn) {
        float g = acc[m][jn][j];
        float u = acc[m][jn + 2][j];
        h[rb2 + wn * 32 + jn * 16 + fr] = (unsigned short)f2bf(g * u / (1.f + __expf(-g)));
      }
    }
}

// ---- shared pipeline macro for gemm2 (unchanged r11 structure)
#define WB(v)                                              \
  do {                                                     \
    asm volatile("s_waitcnt vmcnt(" #v ")" ::: "memory");  \
    __builtin_amdgcn_s_barrier();                          \
    __builtin_amdgcn_sched_barrier(0);                     \
  } while (0)

// ---- kernel D: gemm2: out[t] += rw * (h_e down^T). Tile M128 x N256, 24 halves,
// depth-5 half-ring, vmcnt(6). grid = 8e * 16mt * 4nt = 512.
__global__ __launch_bounds__(512, 2) void gemm2_k(
    const unsigned short* __restrict__ h, const unsigned short* __restrict__ dbf,
    const int* __restrict__ wsI, const float* __restrict__ routw,
    float* __restrict__ out) {
  int e = blockIdx.x & 7, rr = blockIdx.x >> 3;
  int mt = rr & 15, nt = rr >> 4;       // nt 0..3
  int cnt = wsI[e];
  int m0 = mt * 128;
  if (m0 >= cnt) return;
  int base = ebase(wsI, e);
  int n0 = nt * 256;

  __shared__ unsigned short ls[5][12288];   // A[128][32]@0, B[256][32]@4096

  int tid = threadIdx.x, lane = tid & 63, w = tid >> 6;
  int wm = w >> 2, wn = w & 3;
  int fr = lane & 15, fg = lane >> 4;
  int srow = lane >> 2;
  int scol = (((lane & 3) ^ (srow & 3) ^ ((srow >> 2) & 1))) * 8;

  const unsigned short* srcA  = h + (size_t)(base + m0 + 16 * w + srow) * I_DIM + scol;
  const unsigned short* srcB1 = dbf + (size_t)(e * H_DIM + n0 + 16 * w + srow) * I_DIM + scol;
  const unsigned short* srcB2 = dbf + (size_t)(e * H_DIM + n0 + 16 * (w + 8) + srow) * I_DIM + scol;

  int sl = ((fg ^ (fr & 3) ^ ((fr >> 2) & 1)) << 3);
  int roA[4], roB[4];
#pragma unroll
  for (int m = 0; m < 4; ++m) roA[m] = (wm * 64 + m * 16 + fr) * 32 + sl;
#pragma unroll
  for (int n = 0; n < 4; ++n) roB[n] = 4096 + (wn * 64 + n * 16 + fr) * 32 + sl;

  bf16x8 af[2][4], bv[2][4];
  f32x4 acc[4][4] = {};

#define STG2(hh)                                                     \
  do {                                                               \
    unsigned short* lb = &ls[(hh) % 5][0];                           \
    gload16(srcA + (hh) * 32, lb + w * 512);                         \
    gload16(srcB1 + (hh) * 32, lb + 4096 + w * 512);                 \
    gload16(srcB2 + (hh) * 32, lb + 4096 + (w + 8) * 512);           \
  } while (0)
#define LDF2(st, hh)                                                 \
  do {                                                               \
    const unsigned short* lb = &ls[(hh) % 5][0];                     \
    _Pragma("unroll") for (int m = 0; m < 4; ++m) af[st][m] = *(const bf16x8*)(lb + roA[m]); \
    _Pragma("unroll") for (int n = 0; n < 4; ++n) bv[st][n] = *(const bf16x8*)(lb + roB[n]); \
  } while (0)
#define MM2(st)                                                      \
  do {                                                               \
    __builtin_amdgcn_s_setprio(1);                                   \
    _Pragma("unroll") for (int m = 0; m < 4; ++m)                    \
      _Pragma("unroll") for (int n = 0; n < 4; ++n)                  \
        acc[m][n] = __builtin_amdgcn_mfma_f32_16x16x32_bf16(af[st][m], bv[st][n], acc[m][n], 0, 0, 0); \
    __builtin_amdgcn_s_setprio(0);                                   \
  } while (0)

  STG2(0); STG2(1); STG2(2); STG2(3);
  WB(6);
  LDF2(0, 0);
#pragma unroll
  for (int i = 0; i < 24; ++i) {
    if (i + 4 < 24) STG2(i + 4);
    if (i + 1 < 24) LDF2((i + 1) & 1, i + 1);
    MM2(i & 1);
    if (i <= 19)      WB(6);
    else if (i == 20) WB(3);
    else if (i == 21) WB(0);
  }
#undef STG2
#undef LDF2
#undef MM2

#pragma unroll
  for (int m = 0; m < 4; ++m)
#pragma unroll
    for (int j = 0; j < 4; ++j) {
      int row = wm * 64 + m * 16 + fg * 4 + j;
      int grow = m0 + row;
      if (grow < cnt) {
        int tk = wsI[64 + e * T_TOK + grow];
        float rw = routw[(size_t)tk * NEXP + e];
        float* orow = out + (size_t)tk * H_DIM + n0 + wn * 64;
#pragma unroll
        for (int n = 0; n < 4; ++n)
          atomicAdd(orow + n * 16 + fr, acc[m][n][j] * rw);
      }
    }
}

extern "C" void kernel_launch(void* const* d_in, const int* in_sizes, int n_in,
                              void* d_out, int out_size, void* d_ws, size_t ws_size,
                              hipStream_t stream) {
  const float* x      = (const float*)d_in[0];
  const float* gate_w = (const float*)d_in[1];
  const float* up_w   = (const float*)d_in[2];
  const float* down_w = (const float*)d_in[3];
  const float* routw  = (const float*)d_in[4];
  float* out = (float*)d_out;
  int* wsI = (int*)d_ws;

  unsigned short* x_bf = (unsigned short*)((char*)d_ws + 131072);
  unsigned short* gbf  = (unsigned short*)((char*)d_ws + 4458560);
  unsigned short* ubf  = (unsigned short*)((char*)d_ws + 17434688);
  unsigned short* dbf  = (unsigned short*)((char*)d_ws + 30410816);
  unsigned short* h    = (unsigned short*)((char*)d_ws + 42993728);

  compact_k<<<8, 512, 0, stream>>>(routw, wsI);
  pre_k<<<5640, 256, 0, stream>>>(x, gate_w, up_w, down_w, x_bf, gbf, ubf, dbf, out);
  gemm1_k<<<3072, 256, 0, stream>>>(x_bf, gbf, ubf, wsI, h);
  gemm2_k<<<512, 512, 0, stream>>>(h, dbf, wsI, routw, out);
}

// Round 15
// 109.272 us; speedup vs baseline: 1.1580x; 1.1580x over previous
//
#include <hip/hip_runtime.h>
#include <hip/hip_bf16.h>

#define T_TOK 2048
#define H_DIM 1024
#define I_DIM 768
#define NEXP  8
#define XSTR  1056   // padded row stride in shorts (2112B)
#define WSTR  1056

typedef short bf16x8  __attribute__((ext_vector_type(8)));
typedef short short4v __attribute__((ext_vector_type(4)));
typedef float f32x4   __attribute__((ext_vector_type(4)));

__device__ __forceinline__ short f2bf(float f) {
  __bf16 b = (__bf16)f;
  return __builtin_bit_cast(short, b);
}
__device__ __forceinline__ void gload16(const void* g, void* l) {
  __builtin_amdgcn_global_load_lds(
      (const __attribute__((address_space(1))) void*)g,
      (__attribute__((address_space(3))) void*)l, 16, 0, 0);
}
__device__ __forceinline__ void ntst(unsigned short* p, short4v v) {
  __builtin_nontemporal_store(v, (short4v*)p);
}
__device__ __forceinline__ void ntstf(float* p, f32x4 v) {
  __builtin_nontemporal_store(v, (f32x4*)p);
}
__device__ __forceinline__ int padcnt(int c) { return (c + 127) & ~127; }
__device__ __forceinline__ int ebase(const int* __restrict__ cnts, int e) {
  int b = 0;
#pragma unroll
  for (int i = 0; i < NEXP; ++i)
    if (i < e) b += padcnt(cnts[i]);
  return b;
}

// ws layout (bytes):
// 0: counts[8] | 256: lists[8*2048] | 131072: x_bf [2049][1056] (row 2048 = zeros)
// 4458560: gate_bf [6144][1056] | 17434688: up_bf [6144][1056]
// 30410816: down_bf [8192][768] | 42993728: h [5120][768]

// ---- kernel A: routing compaction; pad entries -> token 2048 (zero row)
__global__ __launch_bounds__(512) void compact_k(const float* __restrict__ routw,
                                                 int* __restrict__ wsI) {
  __shared__ int sc[8];
  int e = blockIdx.x, tid = threadIdx.x, lane = tid & 63, w = tid >> 6;
  unsigned long long mk[4];
  int cnt = 0;
#pragma unroll
  for (int c = 0; c < 4; ++c) {
    int tk = w * 256 + c * 64 + lane;
    float v = routw[(size_t)tk * NEXP + e];
    mk[c] = __ballot(v > 0.f);
    cnt += __popcll(mk[c]);
  }
  if (lane == 0) sc[w] = cnt;
  __syncthreads();
  int run = 0, tot = 0;
#pragma unroll
  for (int j = 0; j < 8; ++j) {
    if (j < w) run += sc[j];
    tot += sc[j];
  }
#pragma unroll
  for (int c = 0; c < 4; ++c) {
    int tk = w * 256 + c * 64 + lane;
    if ((mk[c] >> lane) & 1ull) {
      int pos = __popcll(mk[c] & ((1ull << lane) - 1));
      wsI[64 + e * T_TOK + run + pos] = tk;
    }
    run += __popcll(mk[c]);
  }
  if (w == 7 && lane == 0) wsI[e] = tot;
  int pad = padcnt(tot);
  for (int r = tot + tid; r < pad; r += 512) wsI[64 + e * T_TOK + r] = T_TOK;  // zero row
}

// ---- kernel B: all conversions + zerofill, non-temporal stores.
// [0,520): x rows 0..2048 | [520,2056): gate | [2056,3592): up | [3592,5128): down
// [5128,5640): zerofill out
__global__ __launch_bounds__(256) void pre_k(const float* __restrict__ x,
                                             const float* __restrict__ gw,
                                             const float* __restrict__ uw,
                                             const float* __restrict__ dw,
                                             unsigned short* __restrict__ x_bf,
                                             unsigned short* __restrict__ gbf,
                                             unsigned short* __restrict__ ubf,
                                             unsigned short* __restrict__ dbf,
                                             float* __restrict__ out) {
  int bid = blockIdx.x, tid = threadIdx.x;
  int col = (tid & 63) * 16;
  if (bid < 520) {
    int r = bid * 4 + (tid >> 6);
    if (r > 2048) return;
    unsigned short* dst = x_bf + (size_t)r * XSTR + col;
    if (r < 2048) {
      const float* sr = x + (size_t)r * H_DIM + col;
#pragma unroll
      for (int j = 0; j < 4; ++j) {
        float4 v = *(const float4*)(sr + j * 4);
        short4v b = {f2bf(v.x), f2bf(v.y), f2bf(v.z), f2bf(v.w)};
        ntst(dst + j * 4, b);
      }
    } else {
      short4v z = {0, 0, 0, 0};
#pragma unroll
      for (int j = 0; j < 4; ++j) ntst(dst + j * 4, z);
    }
  } else if (bid < 3592) {
    int a = (bid < 2056) ? 0 : 1;
    int r = (bid - (a ? 2056 : 520)) * 4 + (tid >> 6);
    const float* s = (a ? uw : gw) + (size_t)r * H_DIM + col;
    unsigned short* dst = (a ? ubf : gbf) + (size_t)r * WSTR + col;
#pragma unroll
    for (int j = 0; j < 4; ++j) {
      float4 v = *(const float4*)(s + j * 4);
      short4v b = {f2bf(v.x), f2bf(v.y), f2bf(v.z), f2bf(v.w)};
      ntst(dst + j * 4, b);
    }
  } else if (bid < 5128) {
    size_t off = ((size_t)(bid - 3592) * 256 + tid) * 16;
    const float* s = dw + off;
    unsigned short* o = dbf + off;
#pragma unroll
    for (int j = 0; j < 4; ++j) {
      float4 v = *(const float4*)(s + j * 4);
      short4v b = {f2bf(v.x), f2bf(v.y), f2bf(v.z), f2bf(v.w)};
      ntst(o + j * 4, b);
    }
  } else {
    size_t off = ((size_t)(bid - 5128) * 256 + tid) * 16;
    f32x4 z = {0.f, 0.f, 0.f, 0.f};
#pragma unroll
    for (int j = 0; j < 4; ++j) ntstf(out + off + j * 4, z);
  }
}

// ---- kernel C: gemm1: h = silu(X Wg^T)*(X Wu^T).  MINIMUM-2-PHASE, m248 geometry.
// Tile M128 x B128(G64++U64), BK=64, 256 thr / 4 waves, wave tile 64x64
// (each wave: G32+U32 matched cols). 32 MFMA : 16 ds_read / K-tile / wave.
// Per K-tile: issue ALL 8 stage loads FIRST, compute, ONE vmcnt(0)+barrier.
// LDS 2 x 32KB -> 2 blk/CU. grid = 8e * 16mt * 12ng = 1536 (e=bid&7 XCD pin).
__global__ __launch_bounds__(256, 2) void gemm1_k(
    const unsigned short* __restrict__ x_bf, const unsigned short* __restrict__ gbf,
    const unsigned short* __restrict__ ubf, const int* __restrict__ wsI,
    unsigned short* __restrict__ h) {
  int e = blockIdx.x & 7, rr = blockIdx.x >> 3;
  int mt = rr & 15, ng = rr >> 4;       // ng 0..11 (64 G-cols each)
  int cnt = wsI[e];
  int m0 = mt * 128;
  if (m0 >= cnt) return;
  int base = ebase(wsI, e);
  int g0 = ng * 64;

  __shared__ unsigned short ls[2][16384];  // A[128][64]@0, B[128][64]@8192 (shorts)

  int tid = threadIdx.x, lane = tid & 63, w = tid >> 6;   // 4 waves
  int wm = w >> 1, wn = w & 1;
  int fr = lane & 15, fg = lane >> 4;

  // staging: 32 chunks of 8 rows x 128B; wave w -> chunks {w+4i}, i=0..7
  int srow = lane >> 3;                    // row within chunk 0..7
  int scol = ((lane & 7) ^ srow) * 8;      // inverse swizzle (row&7 == srow), shorts
  const unsigned short* src[8];
  int ldo[8];
#pragma unroll
  for (int i = 0; i < 8; ++i) {
    int c = w + 4 * i;
    ldo[i] = c * 512;                      // chunk = 8 rows * 64 shorts
    if (c < 16) {                          // A chunk: per-lane token gather
      int tok = wsI[64 + e * T_TOK + m0 + 8 * c + srow];
      src[i] = x_bf + (size_t)tok * XSTR + scol;
    } else {
      int br = 8 * (c - 16) + srow;        // 0..127: 0-63 G, 64-127 U
      const unsigned short* wp = (br < 64) ? gbf : ubf;
      src[i] = wp + (size_t)(e * I_DIM + g0 + (br & 63)) * WSTR + scol;
    }
  }

  // swizzled read offsets: addr = region + row*64 + (((kh*4+fg) ^ (row&7))<<3)
  int roA[2][4], roB[2][4];
#pragma unroll
  for (int kh = 0; kh < 2; ++kh) {
#pragma unroll
    for (int m = 0; m < 4; ++m) {
      int row = wm * 64 + m * 16 + fr;
      roA[kh][m] = row * 64 + (((kh * 4 + fg) ^ (row & 7)) << 3);
    }
#pragma unroll
    for (int n = 0; n < 4; ++n) {
      int br = (n < 2) ? (wn * 32 + n * 16 + fr) : (64 + wn * 32 + (n - 2) * 16 + fr);
      roB[kh][n] = 8192 + br * 64 + (((kh * 4 + fg) ^ (br & 7)) << 3);
    }
  }

  f32x4 acc[4][4] = {};   // [m][n]: n 0,1 = G; 2,3 = U

#define STG1(buf, t)                                                 \
  do {                                                               \
    _Pragma("unroll") for (int i = 0; i < 8; ++i)                    \
      gload16(src[i] + (t) * 64, &ls[buf][ldo[i]]);                  \
  } while (0)

  STG1(0, 0);
  asm volatile("s_waitcnt vmcnt(0)" ::: "memory");
  __builtin_amdgcn_s_barrier();
  for (int t = 0; t < 16; ++t) {
    int cur = t & 1;
    if (t + 1 < 16) STG1(cur ^ 1, t + 1);   // stage FIRST: flies over whole compute
#pragma unroll
    for (int kh = 0; kh < 2; ++kh) {
      bf16x8 af[4], bv[4];
#pragma unroll
      for (int m = 0; m < 4; ++m) af[m] = *(const bf16x8*)&ls[cur][roA[kh][m]];
#pragma unroll
      for (int n = 0; n < 4; ++n) bv[n] = *(const bf16x8*)&ls[cur][roB[kh][n]];
      __builtin_amdgcn_s_setprio(1);
#pragma unroll
      for (int m = 0; m < 4; ++m)
#pragma unroll
        for (int n = 0; n < 4; ++n)
          acc[m][n] = __builtin_amdgcn_mfma_f32_16x16x32_bf16(af[m], bv[n], acc[m][n], 0, 0, 0);
      __builtin_amdgcn_s_setprio(0);
    }
    asm volatile("s_waitcnt vmcnt(0)" ::: "memory");   // next tile landed
    __builtin_amdgcn_s_barrier();
  }
#undef STG1

#pragma unroll
  for (int m = 0; m < 4; ++m)
#pragma unroll
    for (int j = 0; j < 4; ++j) {
      int row = wm * 64 + m * 16 + fg * 4 + j;   // C/D: col=lane&15, row=(lane>>4)*4+reg
      size_t rb2 = (size_t)(base + m0 + row) * I_DIM + g0;
#pragma unroll
      for (int jn = 0; jn < 2; ++jn) {
        float g = acc[m][jn][j];
        float u = acc[m][jn + 2][j];
        h[rb2 + wn * 32 + jn * 16 + fr] = (unsigned short)f2bf(g * u / (1.f + __expf(-g)));
      }
    }
}

// ---- kernel D: gemm2: out[t] += rw * (h_e down^T). Same minimum-2-phase geometry.
// Tile M128 x N128, BK=64, K=768 (12 tiles), 256 thr / 4 waves, wave 64x64.
// grid = 8e * 16mt * 8nt = 1024.
__global__ __launch_bounds__(256, 2) void gemm2_k(
    const unsigned short* __restrict__ h, const unsigned short* __restrict__ dbf,
    const int* __restrict__ wsI, const float* __restrict__ routw,
    float* __restrict__ out) {
  int e = blockIdx.x & 7, rr = blockIdx.x >> 3;
  int mt = rr & 15, nt = rr >> 4;       // nt 0..7
  int cnt = wsI[e];
  int m0 = mt * 128;
  if (m0 >= cnt) return;
  int base = ebase(wsI, e);
  int n0 = nt * 128;

  __shared__ unsigned short ls[2][16384];  // A[128][64]@0, B[128][64]@8192

  int tid = threadIdx.x, lane = tid & 63, w = tid >> 6;
  int wm = w >> 1, wn = w & 1;
  int fr = lane & 15, fg = lane >> 4;

  int srow = lane >> 3;
  int scol = ((lane & 7) ^ srow) * 8;
  const unsigned short* src[8];
  int ldo[8];
#pragma unroll
  for (int i = 0; i < 8; ++i) {
    int c = w + 4 * i;
    ldo[i] = c * 512;
    if (c < 16) src[i] = h + (size_t)(base + m0 + 8 * c + srow) * I_DIM + scol;
    else        src[i] = dbf + (size_t)(e * H_DIM + n0 + 8 * (c - 16) + srow) * I_DIM + scol;
  }

  int roA[2][4], roB[2][4];
#pragma unroll
  for (int kh = 0; kh < 2; ++kh) {
#pragma unroll
    for (int m = 0; m < 4; ++m) {
      int row = wm * 64 + m * 16 + fr;
      roA[kh][m] = row * 64 + (((kh * 4 + fg) ^ (row & 7)) << 3);
    }
#pragma unroll
    for (int n = 0; n < 4; ++n) {
      int br = wn * 64 + n * 16 + fr;
      roB[kh][n] = 8192 + br * 64 + (((kh * 4 + fg) ^ (br & 7)) << 3);
    }
  }

  f32x4 acc[4][4] = {};

#define STG2(buf, t)                                                 \
  do {                                                               \
    _Pragma("unroll") for (int i = 0; i < 8; ++i)                    \
      gload16(src[i] + (t) * 64, &ls[buf][ldo[i]]);                  \
  } while (0)

  STG2(0, 0);
  asm volatile("s_waitcnt vmcnt(0)" ::: "memory");
  __builtin_amdgcn_s_barrier();
  for (int t = 0; t < 12; ++t) {
    int cur = t & 1;
    if (t + 1 < 12) STG2(cur ^ 1, t + 1);
#pragma unroll
    for (int kh = 0; kh < 2; ++kh) {
      bf16x8 af[4], bv[4];
#pragma unroll
      for (int m = 0; m < 4; ++m) af[m] = *(const bf16x8*)&ls[cur][roA[kh][m]];
#pragma unroll
      for (int n = 0; n < 4; ++n) bv[n] = *(const bf16x8*)&ls[cur][roB[kh][n]];
      __builtin_amdgcn_s_setprio(1);
#pragma unroll
      for (int m = 0; m < 4; ++m)
#pragma unroll
        for (int n = 0; n < 4; ++n)
          acc[m][n] = __builtin_amdgcn_mfma_f32_16x16x32_bf16(af[m], bv[n], acc[m][n], 0, 0, 0);
      __builtin_amdgcn_s_setprio(0);
    }
    asm volatile("s_waitcnt vmcnt(0)" ::: "memory");
    __builtin_amdgcn_s_barrier();
  }
#undef STG2

#pragma unroll
  for (int m = 0; m < 4; ++m)
#pragma unroll
    for (int j = 0; j < 4; ++j) {
      int row = wm * 64 + m * 16 + fg * 4 + j;
      int grow = m0 + row;
      if (grow < cnt) {
        int tk = wsI[64 + e * T_TOK + grow];
        float rw = routw[(size_t)tk * NEXP + e];
        float* orow = out + (size_t)tk * H_DIM + n0 + wn * 64;
#pragma unroll
        for (int n = 0; n < 4; ++n)
          atomicAdd(orow + n * 16 + fr, acc[m][n][j] * rw);
      }
    }
}

extern "C" void kernel_launch(void* const* d_in, const int* in_sizes, int n_in,
                              void* d_out, int out_size, void* d_ws, size_t ws_size,
                              hipStream_t stream) {
  const float* x      = (const float*)d_in[0];
  const float* gate_w = (const float*)d_in[1];
  const float* up_w   = (const float*)d_in[2];
  const float* down_w = (const float*)d_in[3];
  const float* routw  = (const float*)d_in[4];
  float* out = (float*)d_out;
  int* wsI = (int*)d_ws;

  unsigned short* x_bf = (unsigned short*)((char*)d_ws + 131072);
  unsigned short* gbf  = (unsigned short*)((char*)d_ws + 4458560);
  unsigned short* ubf  = (unsigned short*)((char*)d_ws + 17434688);
  unsigned short* dbf  = (unsigned short*)((char*)d_ws + 30410816);
  unsigned short* h    = (unsigned short*)((char*)d_ws + 42993728);

  compact_k<<<8, 512, 0, stream>>>(routw, wsI);
  pre_k<<<5640, 256, 0, stream>>>(x, gate_w, up_w, down_w, x_bf, gbf, ubf, dbf, out);
  gemm1_k<<<1536, 256, 0, stream>>>(x_bf, gbf, ubf, wsI, h);
  gemm2_k<<<1024, 256, 0, stream>>>(h, dbf, wsI, routw, out);
}

// Round 16
// 103.426 us; speedup vs baseline: 1.2235x; 1.0565x over previous
//
#include <hip/hip_runtime.h>
#include <hip/hip_bf16.h>

#define T_TOK 2048
#define H_DIM 1024
#define I_DIM 768
#define NEXP  8
#define XSTR  1056   // padded x row stride in shorts

typedef short bf16x8  __attribute__((ext_vector_type(8)));
typedef short short4v __attribute__((ext_vector_type(4)));
typedef float f32x4   __attribute__((ext_vector_type(4)));

__device__ __forceinline__ short f2bf(float f) {
  __bf16 b = (__bf16)f;
  return __builtin_bit_cast(short, b);
}
__device__ __forceinline__ void gload16(const void* g, void* l) {
  __builtin_amdgcn_global_load_lds(
      (const __attribute__((address_space(1))) void*)g,
      (__attribute__((address_space(3))) void*)l, 16, 0, 0);
}
__device__ __forceinline__ void ntst(unsigned short* p, short4v v) {
  __builtin_nontemporal_store(v, (short4v*)p);
}
__device__ __forceinline__ void ntstf(float* p, f32x4 v) {
  __builtin_nontemporal_store(v, (f32x4*)p);
}
__device__ __forceinline__ int padcnt(int c) { return (c + 127) & ~127; }
__device__ __forceinline__ int ebase(const int* __restrict__ cnts, int e) {
  int b = 0;
#pragma unroll
  for (int i = 0; i < NEXP; ++i)
    if (i < e) b += padcnt(cnts[i]);
  return b;
}

// ws layout (bytes): 0: counts[8] | 256: lists[8*2048]
// 131072: x_bf [2049][1056] (row 2048 = zeros) | 4458560: h [5120][768]

// ---- kernel A: routing compaction; pad entries -> token 2048 (zero row)
__global__ __launch_bounds__(512) void compact_k(const float* __restrict__ routw,
                                                 int* __restrict__ wsI) {
  __shared__ int sc[8];
  int e = blockIdx.x, tid = threadIdx.x, lane = tid & 63, w = tid >> 6;
  unsigned long long mk[4];
  int cnt = 0;
#pragma unroll
  for (int c = 0; c < 4; ++c) {
    int tk = w * 256 + c * 64 + lane;
    float v = routw[(size_t)tk * NEXP + e];
    mk[c] = __ballot(v > 0.f);
    cnt += __popcll(mk[c]);
  }
  if (lane == 0) sc[w] = cnt;
  __syncthreads();
  int run = 0, tot = 0;
#pragma unroll
  for (int j = 0; j < 8; ++j) {
    if (j < w) run += sc[j];
    tot += sc[j];
  }
#pragma unroll
  for (int c = 0; c < 4; ++c) {
    int tk = w * 256 + c * 64 + lane;
    if ((mk[c] >> lane) & 1ull) {
      int pos = __popcll(mk[c] & ((1ull << lane) - 1));
      wsI[64 + e * T_TOK + run + pos] = tk;
    }
    run += __popcll(mk[c]);
  }
  if (w == 7 && lane == 0) wsI[e] = tot;
  int pad = padcnt(tot);
  for (int r = tot + tid; r < pad; r += 512) wsI[64 + e * T_TOK + r] = T_TOK;
}

// ---- kernel B: x conv + zerofill ONLY (weight conversion now fused into GEMMs)
// [0,520): x rows 0..2048 | [520,1032): zerofill out
__global__ __launch_bounds__(256) void pre_k(const float* __restrict__ x,
                                             unsigned short* __restrict__ x_bf,
                                             float* __restrict__ out) {
  int bid = blockIdx.x, tid = threadIdx.x;
  int col = (tid & 63) * 16;
  if (bid < 520) {
    int r = bid * 4 + (tid >> 6);
    if (r > 2048) return;
    unsigned short* dst = x_bf + (size_t)r * XSTR + col;
    if (r < 2048) {
      const float* sr = x + (size_t)r * H_DIM + col;
#pragma unroll
      for (int j = 0; j < 4; ++j) {
        float4 v = *(const float4*)(sr + j * 4);
        short4v b = {f2bf(v.x), f2bf(v.y), f2bf(v.z), f2bf(v.w)};
        ntst(dst + j * 4, b);
      }
    } else {
      short4v z = {0, 0, 0, 0};
#pragma unroll
      for (int j = 0; j < 4; ++j) ntst(dst + j * 4, z);
    }
  } else {
    size_t off = ((size_t)(bid - 520) * 256 + tid) * 16;
    f32x4 z = {0.f, 0.f, 0.f, 0.f};
#pragma unroll
    for (int j = 0; j < 4; ++j) ntstf(out + off + j * 4, z);
  }
}

// ---- kernel C: gemm1: h = silu(X Wg^T)*(X Wu^T). Minimum-2-phase (r15 schedule),
// B operand read DIRECTLY from fp32 gate/up and converted during staging
// (global fp32 -> regs -> cvt -> ds_write_b128). A = x_bf via gload_lds + XOR swizzle.
// B LDS rows use 144B stride (72 shorts): banks rotate +4/row -> conflict-free, no XOR.
// Tile M128 x B128(G64++U64), BK=64, 256 thr/4 waves, wave 64x64. LDS 2x34KB.
// grid = 8e * 16mt * 12ng = 1536.
__global__ __launch_bounds__(256, 2) void gemm1_k(
    const unsigned short* __restrict__ x_bf, const float* __restrict__ gw,
    const float* __restrict__ uw, const int* __restrict__ wsI,
    unsigned short* __restrict__ h) {
  int e = blockIdx.x & 7, rr = blockIdx.x >> 3;
  int mt = rr & 15, ng = rr >> 4;       // ng 0..11 (64 G-cols)
  int cnt = wsI[e];
  int m0 = mt * 128;
  if (m0 >= cnt) return;
  int base = ebase(wsI, e);
  int g0 = ng * 64;

  __shared__ unsigned short ls[2][17408];  // A[128][64]@0 (8192), B[128] rows x 72 @8192

  int tid = threadIdx.x, lane = tid & 63, w = tid >> 6;
  int wm = w >> 1, wn = w & 1;
  int fr = lane & 15, fg = lane >> 4;
  int srow = lane >> 3;                    // 0..7
  int scolA = ((lane & 7) ^ srow) * 8;     // A inverse swizzle (shorts)

  // A: 16 chunks of 8 rows x 128B, wave w -> {w+4i}; per-lane token gather
  const unsigned short* srcA[4];
  int ldoA[4];
#pragma unroll
  for (int i = 0; i < 4; ++i) {
    int c = w + 4 * i;
    ldoA[i] = c * 512;
    int tok = wsI[64 + e * T_TOK + m0 + 8 * c + srow];
    srcA[i] = x_bf + (size_t)tok * XSTR + scolA;
  }
  // B: 16 chunks of 8 rows; rows 0-63 = gate g0.., 64-127 = up g0..; fp32 source
  const float* srcB[4];
  int wOffB[4];
#pragma unroll
  for (int i = 0; i < 4; ++i) {
    int cidx = w + 4 * i;
    int br = 8 * cidx + srow;
    const float* wp = (br < 64) ? gw : uw;
    srcB[i] = wp + (size_t)(e * I_DIM + g0 + (br & 63)) * H_DIM + (lane & 7) * 8;
    wOffB[i] = 8192 + br * 72 + (lane & 7) * 8;
  }

  int roA[2][4], roB[2][4];
#pragma unroll
  for (int kh = 0; kh < 2; ++kh) {
#pragma unroll
    for (int m = 0; m < 4; ++m) {
      int row = wm * 64 + m * 16 + fr;
      roA[kh][m] = row * 64 + (((kh * 4 + fg) ^ (row & 7)) << 3);
    }
#pragma unroll
    for (int n = 0; n < 4; ++n) {
      int br = (n < 2) ? (wn * 32 + n * 16 + fr) : (64 + wn * 32 + (n - 2) * 16 + fr);
      roB[kh][n] = 8192 + br * 72 + (kh * 4 + fg) * 8;
    }
  }

  f32x4 acc[4][4] = {};   // [m][n]: n 0,1 = G; 2,3 = U
  float4 fb[4][2];

#define BLOAD1(t)                                                    \
  do {                                                               \
    _Pragma("unroll") for (int i = 0; i < 4; ++i) {                  \
      fb[i][0] = *(const float4*)(srcB[i] + (t) * 64);               \
      fb[i][1] = *(const float4*)(srcB[i] + (t) * 64 + 4);           \
    }                                                                \
  } while (0)
#define AGL1(buf, t)                                                 \
  do {                                                               \
    _Pragma("unroll") for (int i = 0; i < 4; ++i)                    \
      gload16(srcA[i] + (t) * 64, &ls[buf][ldoA[i]]);                \
  } while (0)
#define CVTW1(buf)                                                   \
  do {                                                               \
    _Pragma("unroll") for (int i = 0; i < 4; ++i) {                  \
      bf16x8 v = {f2bf(fb[i][0].x), f2bf(fb[i][0].y), f2bf(fb[i][0].z), f2bf(fb[i][0].w), \
                  f2bf(fb[i][1].x), f2bf(fb[i][1].y), f2bf(fb[i][1].z), f2bf(fb[i][1].w)}; \
      *(bf16x8*)&ls[buf][wOffB[i]] = v;                              \
    }                                                                \
  } while (0)
#define CMP1(cur)                                                    \
  do {                                                               \
    _Pragma("unroll") for (int kh = 0; kh < 2; ++kh) {               \
      bf16x8 af[4], bv[4];                                           \
      _Pragma("unroll") for (int m = 0; m < 4; ++m) af[m] = *(const bf16x8*)&ls[cur][roA[kh][m]]; \
      _Pragma("unroll") for (int n = 0; n < 4; ++n) bv[n] = *(const bf16x8*)&ls[cur][roB[kh][n]]; \
      __builtin_amdgcn_s_setprio(1);                                 \
      _Pragma("unroll") for (int m = 0; m < 4; ++m)                  \
        _Pragma("unroll") for (int n = 0; n < 4; ++n)                \
          acc[m][n] = __builtin_amdgcn_mfma_f32_16x16x32_bf16(af[m], bv[n], acc[m][n], 0, 0, 0); \
      __builtin_amdgcn_s_setprio(0);                                 \
    }                                                                \
  } while (0)

  BLOAD1(0);
  AGL1(0, 0);
  asm volatile("s_waitcnt vmcnt(0)" ::: "memory");
  CVTW1(0);
  asm volatile("s_waitcnt lgkmcnt(0)" ::: "memory");
  __builtin_amdgcn_s_barrier();
  for (int t = 0; t < 16; ++t) {
    int cur = t & 1;
    if (t + 1 < 16) {
      BLOAD1(t + 1);                   // fp32 B loads fly over the whole compute
      AGL1(cur ^ 1, t + 1);            // A direct-to-LDS
    }
    CMP1(cur);
    if (t + 1 < 16) {
      asm volatile("s_waitcnt vmcnt(0)" ::: "memory");
      CVTW1(cur ^ 1);
      asm volatile("s_waitcnt lgkmcnt(0)" ::: "memory");
    }
    __builtin_amdgcn_s_barrier();
  }
#undef BLOAD1
#undef AGL1
#undef CVTW1
#undef CMP1

#pragma unroll
  for (int m = 0; m < 4; ++m)
#pragma unroll
    for (int j = 0; j < 4; ++j) {
      int row = wm * 64 + m * 16 + fg * 4 + j;   // C/D: col=lane&15, row=(lane>>4)*4+reg
      size_t rb2 = (size_t)(base + m0 + row) * I_DIM + g0;
#pragma unroll
      for (int jn = 0; jn < 2; ++jn) {
        float g = acc[m][jn][j];
        float u = acc[m][jn + 2][j];
        h[rb2 + wn * 32 + jn * 16 + fr] = (unsigned short)f2bf(g * u / (1.f + __expf(-g)));
      }
    }
}

// ---- kernel D: gemm2: out[t] += rw * (h_e down^T). Same fused-conversion scheme:
// A = h bf16 via gload_lds+XOR; B = down fp32 reg-staged into 144B-stride LDS.
// Tile M128 x N128, BK=64, K=768 (12 tiles). grid = 8e * 16mt * 8nt = 1024.
__global__ __launch_bounds__(256, 2) void gemm2_k(
    const unsigned short* __restrict__ h, const float* __restrict__ dw,
    const int* __restrict__ wsI, const float* __restrict__ routw,
    float* __restrict__ out) {
  int e = blockIdx.x & 7, rr = blockIdx.x >> 3;
  int mt = rr & 15, nt = rr >> 4;       // nt 0..7
  int cnt = wsI[e];
  int m0 = mt * 128;
  if (m0 >= cnt) return;
  int base = ebase(wsI, e);
  int n0 = nt * 128;

  __shared__ unsigned short ls[2][17408];

  int tid = threadIdx.x, lane = tid & 63, w = tid >> 6;
  int wm = w >> 1, wn = w & 1;
  int fr = lane & 15, fg = lane >> 4;
  int srow = lane >> 3;
  int scolA = ((lane & 7) ^ srow) * 8;

  const unsigned short* srcA[4];
  int ldoA[4];
#pragma unroll
  for (int i = 0; i < 4; ++i) {
    int c = w + 4 * i;
    ldoA[i] = c * 512;
    srcA[i] = h + (size_t)(base + m0 + 8 * c + srow) * I_DIM + scolA;
  }
  const float* srcB[4];
  int wOffB[4];
#pragma unroll
  for (int i = 0; i < 4; ++i) {
    int cidx = w + 4 * i;
    int br = 8 * cidx + srow;
    srcB[i] = dw + (size_t)(e * H_DIM + n0 + br) * I_DIM + (lane & 7) * 8;
    wOffB[i] = 8192 + br * 72 + (lane & 7) * 8;
  }

  int roA[2][4], roB[2][4];
#pragma unroll
  for (int kh = 0; kh < 2; ++kh) {
#pragma unroll
    for (int m = 0; m < 4; ++m) {
      int row = wm * 64 + m * 16 + fr;
      roA[kh][m] = row * 64 + (((kh * 4 + fg) ^ (row & 7)) << 3);
    }
#pragma unroll
    for (int n = 0; n < 4; ++n) {
      int br = wn * 64 + n * 16 + fr;
      roB[kh][n] = 8192 + br * 72 + (kh * 4 + fg) * 8;
    }
  }

  f32x4 acc[4][4] = {};
  float4 fb[4][2];

#define BLOAD2(t)                                                    \
  do {                                                               \
    _Pragma("unroll") for (int i = 0; i < 4; ++i) {                  \
      fb[i][0] = *(const float4*)(srcB[i] + (t) * 64);               \
      fb[i][1] = *(const float4*)(srcB[i] + (t) * 64 + 4);           \
    }                                                                \
  } while (0)
#define AGL2(buf, t)                                                 \
  do {                                                               \
    _Pragma("unroll") for (int i = 0; i < 4; ++i)                    \
      gload16(srcA[i] + (t) * 64, &ls[buf][ldoA[i]]);                \
  } while (0)
#define CVTW2(buf)                                                   \
  do {                                                               \
    _Pragma("unroll") for (int i = 0; i < 4; ++i) {                  \
      bf16x8 v = {f2bf(fb[i][0].x), f2bf(fb[i][0].y), f2bf(fb[i][0].z), f2bf(fb[i][0].w), \
                  f2bf(fb[i][1].x), f2bf(fb[i][1].y), f2bf(fb[i][1].z), f2bf(fb[i][1].w)}; \
      *(bf16x8*)&ls[buf][wOffB[i]] = v;                              \
    }                                                                \
  } while (0)
#define CMP2(cur)                                                    \
  do {                                                               \
    _Pragma("unroll") for (int kh = 0; kh < 2; ++kh) {               \
      bf16x8 af[4], bv[4];                                           \
      _Pragma("unroll") for (int m = 0; m < 4; ++m) af[m] = *(const bf16x8*)&ls[cur][roA[kh][m]]; \
      _Pragma("unroll") for (int n = 0; n < 4; ++n) bv[n] = *(const bf16x8*)&ls[cur][roB[kh][n]]; \
      __builtin_amdgcn_s_setprio(1);                                 \
      _Pragma("unroll") for (int m = 0; m < 4; ++m)                  \
        _Pragma("unroll") for (int n = 0; n < 4; ++n)                \
          acc[m][n] = __builtin_amdgcn_mfma_f32_16x16x32_bf16(af[m], bv[n], acc[m][n], 0, 0, 0); \
      __builtin_amdgcn_s_setprio(0);                                 \
    }                                                                \
  } while (0)

  BLOAD2(0);
  AGL2(0, 0);
  asm volatile("s_waitcnt vmcnt(0)" ::: "memory");
  CVTW2(0);
  asm volatile("s_waitcnt lgkmcnt(0)" ::: "memory");
  __builtin_amdgcn_s_barrier();
  for (int t = 0; t < 12; ++t) {
    int cur = t & 1;
    if (t + 1 < 12) {
      BLOAD2(t + 1);
      AGL2(cur ^ 1, t + 1);
    }
    CMP2(cur);
    if (t + 1 < 12) {
      asm volatile("s_waitcnt vmcnt(0)" ::: "memory");
      CVTW2(cur ^ 1);
      asm volatile("s_waitcnt lgkmcnt(0)" ::: "memory");
    }
    __builtin_amdgcn_s_barrier();
  }
#undef BLOAD2
#undef AGL2
#undef CVTW2
#undef CMP2

#pragma unroll
  for (int m = 0; m < 4; ++m)
#pragma unroll
    for (int j = 0; j < 4; ++j) {
      int row = wm * 64 + m * 16 + fg * 4 + j;
      int grow = m0 + row;
      if (grow < cnt) {
        int tk = wsI[64 + e * T_TOK + grow];
        float rw = routw[(size_t)tk * NEXP + e];
        float* orow = out + (size_t)tk * H_DIM + n0 + wn * 64;
#pragma unroll
        for (int n = 0; n < 4; ++n)
          atomicAdd(orow + n * 16 + fr, acc[m][n][j] * rw);
      }
    }
}

extern "C" void kernel_launch(void* const* d_in, const int* in_sizes, int n_in,
                              void* d_out, int out_size, void* d_ws, size_t ws_size,
                              hipStream_t stream) {
  const float* x      = (const float*)d_in[0];
  const float* gate_w = (const float*)d_in[1];
  const float* up_w   = (const float*)d_in[2];
  const float* down_w = (const float*)d_in[3];
  const float* routw  = (const float*)d_in[4];
  float* out = (float*)d_out;
  int* wsI = (int*)d_ws;

  unsigned short* x_bf = (unsigned short*)((char*)d_ws + 131072);
  unsigned short* h    = (unsigned short*)((char*)d_ws + 4458560);

  compact_k<<<8, 512, 0, stream>>>(routw, wsI);
  pre_k<<<1032, 256, 0, stream>>>(x, x_bf, out);
  gemm1_k<<<1536, 256, 0, stream>>>(x_bf, gate_w, up_w, wsI, h);
  gemm2_k<<<1024, 256, 0, stream>>>(h, down_w, wsI, routw, out);
}